// Round 12
// baseline (613.646 us; speedup 1.0000x reference)
//
#include <hip/hip_runtime.h>
#include <math.h>

#define NN 30000
#define NE 480000

typedef _Float16 f16x8 __attribute__((ext_vector_type(8)));
typedef _Float16 f16x4 __attribute__((ext_vector_type(4)));
typedef _Float16 f16x2 __attribute__((ext_vector_type(2)));
typedef float f32x4 __attribute__((ext_vector_type(4)));

// async global->LDS, 16B per lane, wave-uniform LDS base + lane*16
#define GLOAD_LDS16(gp, lp)                                        \
    __builtin_amdgcn_global_load_lds(                              \
        (const __attribute__((address_space(1))) void*)(gp),       \
        (__attribute__((address_space(3))) void*)(lp), 16, 0, 0)

// ---------------- mega prep kernel (validated round 10: coalesced only) ----
// jobs (by blockIdx.x range, 256 threads each):
//  A [0,7500)        cvt x f32->f16 (8/thread)
//  B [7500,7692)     cvt W1 [512][768] f32->f16 (8/thread)
//  C [7692,7788)     cvt W2 [256][768] f32->f16
//  D [7788,8556)     build RT1 [768][768] f16 (row m = out col, [K|Q|V])
//  E [8556,9324)     build RT2 [768][768] f16
//  F [9324,9327)     foldb1 -> bf1[768]
//  G [9327,9330)     foldb2 -> bf2[768]
//  H [9330,9586)     tcvt w_out1 -> wout1T
//  I [9586,9842)     tcvt w_out2 -> wout2T
//  J [9842,9960)     zero deg[NN]
//  K [9960,9962)     zero bnstats[512]
#define PREP_BLOCKS 9962
__global__ __launch_bounds__(256) void prep_kernel(
    const float* __restrict__ x, _Float16* __restrict__ x_h,
    const float* __restrict__ w_kqv1, _Float16* __restrict__ w1h,
    const float* __restrict__ w_kqv2, _Float16* __restrict__ w2h,
    const float* __restrict__ krel, const float* __restrict__ vrel,
    const float* __restrict__ krel2, const float* __restrict__ vrel2,
    _Float16* __restrict__ rt1, _Float16* __restrict__ rt2,
    const float* __restrict__ b_kqv1, float* __restrict__ bf1,
    const float* __restrict__ b_kqv2, float* __restrict__ bf2,
    const float* __restrict__ w_out1, _Float16* __restrict__ wout1T,
    const float* __restrict__ w_out2, _Float16* __restrict__ wout2T,
    int* __restrict__ deg, float* __restrict__ bnstats)
{
    const int bid = blockIdx.x, tid = threadIdx.x;
    if (bid < 7500) {                       // A: cvt x (8 elems/thread)
        long i = (long)bid * 256 + tid;     // < 1,920,000
        float4 a = ((const float4*)x)[2 * i];
        float4 b = ((const float4*)x)[2 * i + 1];
        f16x8 o = {(_Float16)a.x, (_Float16)a.y, (_Float16)a.z, (_Float16)a.w,
                   (_Float16)b.x, (_Float16)b.y, (_Float16)b.z, (_Float16)b.w};
        ((f16x8*)x_h)[i] = o;
    } else if (bid < 7692) {                // B: cvt W1 (393216 floats)
        long i = (long)(bid - 7500) * 256 + tid;
        float4 a = ((const float4*)w_kqv1)[2 * i];
        float4 b = ((const float4*)w_kqv1)[2 * i + 1];
        f16x8 o = {(_Float16)a.x, (_Float16)a.y, (_Float16)a.z, (_Float16)a.w,
                   (_Float16)b.x, (_Float16)b.y, (_Float16)b.z, (_Float16)b.w};
        ((f16x8*)w1h)[i] = o;
    } else if (bid < 7788) {                // C: cvt W2 (196608 floats)
        long i = (long)(bid - 7692) * 256 + tid;
        float4 a = ((const float4*)w_kqv2)[2 * i];
        float4 b = ((const float4*)w_kqv2)[2 * i + 1];
        f16x8 o = {(_Float16)a.x, (_Float16)a.y, (_Float16)a.z, (_Float16)a.w,
                   (_Float16)b.x, (_Float16)b.y, (_Float16)b.z, (_Float16)b.w};
        ((f16x8*)w2h)[i] = o;
    } else if (bid < 8556) {                // D: build RT1, row m = bid-7788
        int m = bid - 7788;
#pragma unroll
        for (int rep = 0; rep < 3; ++rep) {
            int d = tid + rep * 256;
            _Float16 val = (_Float16)0.0f;
            if (m < 256) {
                if (d < 256 && (d >> 6) == (m >> 6))
                    val = (_Float16)krel[(m >> 6) * 4096 + (d & 63) * 64 + (m & 63)];
            } else if (m < 512) {
                if (d == m) val = (_Float16)1.0f;
            } else {
                if (d >= 512 && ((d - 512) >> 6) == ((m - 512) >> 6))
                    val = (_Float16)vrel[((m - 512) >> 6) * 4096 +
                                         ((d - 512) & 63) * 64 + ((m - 512) & 63)];
            }
            rt1[(long)m * 768 + d] = val;
        }
    } else if (bid < 9324) {                // E: build RT2, row m = bid-8556
        int m = bid - 8556;
#pragma unroll
        for (int rep = 0; rep < 3; ++rep) {
            int d = tid + rep * 256;
            _Float16 val = (_Float16)0.0f;
            if (m < 256) {
                if (d < 256) val = (_Float16)krel2[(long)d * 256 + m];
            } else if (m < 512) {
                if (d == m) val = (_Float16)1.0f;
            } else {
                if (d >= 512) val = (_Float16)vrel2[(long)(d - 512) * 256 + (m - 512)];
            }
            rt2[(long)m * 768 + d] = val;
        }
    } else if (bid < 9327) {                // F: foldb1 ([K|Q|V])
        int n = (bid - 9324) * 256 + tid;
        float acc;
        if (n < 256) {
            int h = n >> 6, e = n & 63;
            acc = 0.f;
            for (int d = 0; d < 64; ++d) acc += b_kqv1[h * 64 + d] * krel[h * 4096 + d * 64 + e];
        } else if (n < 512) {
            acc = b_kqv1[n];
        } else {
            int m2 = n - 512, h = m2 >> 6, e = m2 & 63;
            acc = 0.f;
            for (int d = 0; d < 64; ++d) acc += b_kqv1[512 + h * 64 + d] * vrel[h * 4096 + d * 64 + e];
        }
        bf1[n] = acc;
    } else if (bid < 9330) {                // G: foldb2
        int n = (bid - 9327) * 256 + tid;
        float acc;
        if (n < 256) {
            acc = 0.f;
            for (int d = 0; d < 256; ++d) acc += b_kqv2[d] * krel2[(long)d * 256 + n];
        } else if (n < 512) {
            acc = b_kqv2[n];
        } else {
            acc = 0.f;
            for (int d = 0; d < 256; ++d) acc += b_kqv2[512 + d] * vrel2[(long)d * 256 + (n - 512)];
        }
        bf2[n] = acc;
    } else if (bid < 9586) {                // H: tcvt w_out1
        int k = bid - 9330;
        int n = tid;
        wout1T[(long)n * 256 + k] = (_Float16)w_out1[(long)k * 256 + n];
    } else if (bid < 9842) {                // I: tcvt w_out2
        int k = bid - 9586;
        int n = tid;
        wout2T[(long)n * 256 + k] = (_Float16)w_out2[(long)k * 256 + n];
    } else if (bid < 9960) {                // J: zero deg
        int i = (bid - 9842) * 256 + tid;
        if (i < NN) deg[i] = 0;
    } else {                                // K: zero bnstats
        int i = (bid - 9960) * 256 + tid;
        if (i < 512) bnstats[i] = 0.0f;
    }
}

// ---------------- CSR build ----------------
__global__ void deg_kernel(const int* __restrict__ dst, int* __restrict__ deg, int e) {
    int i = blockIdx.x * blockDim.x + threadIdx.x;
    if (i < e) atomicAdd(&deg[dst[i]], 1);
}

__global__ __launch_bounds__(1024) void scan_kernel(
    const int* __restrict__ deg, int* __restrict__ row_start,
    int* __restrict__ pos, int n)
{
    __shared__ int smem[1024];
    const int t = threadIdx.x;
    const int base = t * 32;  // 1024*32 = 32768 >= 30000
    int loc[32];
    int s = 0;
#pragma unroll
    for (int g = 0; g < 8; ++g) {
        int idx = base + g * 4;
        int4 d4;
        if (idx + 3 < n) {
            d4 = *(const int4*)(deg + idx);
        } else {
            d4.x = (idx + 0 < n) ? deg[idx + 0] : 0;
            d4.y = (idx + 1 < n) ? deg[idx + 1] : 0;
            d4.z = (idx + 2 < n) ? deg[idx + 2] : 0;
            d4.w = (idx + 3 < n) ? deg[idx + 3] : 0;
        }
        loc[g * 4 + 0] = s; s += d4.x;
        loc[g * 4 + 1] = s; s += d4.y;
        loc[g * 4 + 2] = s; s += d4.z;
        loc[g * 4 + 3] = s; s += d4.w;
    }
    smem[t] = s;
    __syncthreads();
    for (int off = 1; off < 1024; off <<= 1) {
        int tv = 0;
        if (t >= off) tv = smem[t - off];
        __syncthreads();
        smem[t] += tv;
        __syncthreads();
    }
    const int excl = smem[t] - s;
#pragma unroll
    for (int g = 0; g < 32; ++g) {
        int idx = base + g;
        if (idx < n) {
            int r = excl + loc[g];
            row_start[idx] = r;
            pos[idx] = r;
        }
    }
    if (t == 1023) row_start[n] = smem[1023];
}

__global__ void fill_kernel(const int* __restrict__ src, const int* __restrict__ dst,
                            int* __restrict__ pos, int* __restrict__ csr_src, int e) {
    int i = blockIdx.x * blockDim.x + threadIdx.x;
    if (i < e) {
        int p = atomicAdd(&pos[dst[i]], 1);
        csr_src[p] = src[i];
    }
}

// ---------------- fp16 MFMA GEMM: double-buffered global_load_lds prefetch +
// TILE LOOP (persistent-style): grid = min(ntiles, 1024) = full residency;
// each block strides over tiles, eliminating the partial-round tail
// (1410 tiles @ 4 blocks/CU = 1024 resident -> was 2 rounds, now 1.38). ----
__global__ __launch_bounds__(256) void mfma_gemm_kernel(
    const _Float16* __restrict__ A, int lda,
    const _Float16* __restrict__ BT,
    float* __restrict__ Cf,
    _Float16* __restrict__ Ch,
    int ldc, int M, int N, int K,
    int ntx, int nty,                   // tile grid (N/128, ceil(M/128))
    const float* __restrict__ bias,
    const _Float16* __restrict__ res,   // f16 residual (skip blend), ld = ldc
    const float* __restrict__ skip,
    float* __restrict__ bn_accum)       // [512]: col sums then col sqsums
{
    __shared__ __align__(16) _Float16 As[2][128][32];
    __shared__ __align__(16) _Float16 Bs[2][128][32];
    const int tid = threadIdx.x;
    const int wave = tid >> 6, lane = tid & 63;
    const int wr = wave >> 1, wc = wave & 1;
    const int l16 = lane & 15, quad = lane >> 4;
    const int r0 = tid >> 2, kc0 = (tid & 3) * 8;
    const int r1 = r0 + 64;

    auto lds = (__attribute__((address_space(3))) char*)&As[0][0][0];
    // byte offsets: As[buf] at buf*8192; Bs[buf] at 16384 + buf*8192
    const int wb = wave * 1024;  // wave-uniform LDS base (lane*16 added by HW)
    const int nt = K >> 5;
    const int ntiles = ntx * nty;

    float s = 1.0f, om = 0.0f;
    if (skip) {
        float sv = 1.0f / (1.0f + __expf(-skip[0]));
        s = sv; om = 1.0f - sv;
    }

    for (int tile = blockIdx.x; tile < ntiles; tile += gridDim.x) {
        const int bn0 = (tile % ntx) * 128;
        const int bm = (tile / ntx) * 128;
        int gra0 = bm + r0; if (gra0 >= M) gra0 = M - 1;  // DMA has no predication;
        int gra1 = bm + r1; if (gra1 >= M) gra1 = M - 1;  // C-store is row-guarded
        const _Float16* a0 = A + (long)gra0 * lda + kc0;
        const _Float16* a1 = A + (long)gra1 * lda + kc0;
        const _Float16* b0 = BT + (long)(bn0 + r0) * K + kc0;
        const _Float16* b1 = BT + (long)(bn0 + r1) * K + kc0;

        if (tile != (int)blockIdx.x) __syncthreads();  // LDS reuse guard across tiles

        f32x4 acc[4][4] = {};

        // prologue: stage tile 0 into buf 0
        GLOAD_LDS16(a0, lds + wb);
        GLOAD_LDS16(a1, lds + 4096 + wb);
        GLOAD_LDS16(b0, lds + 16384 + wb);
        GLOAD_LDS16(b1, lds + 16384 + 4096 + wb);
        __syncthreads();

        int cur = 0;
        for (int t = 0; t < nt; ++t) {
            if (t + 1 < nt) {  // issue next tile's DMAs BEFORE compute (overlap)
                const int k1 = (t + 1) << 5;
                const int nb = (cur ^ 1) * 8192;
                GLOAD_LDS16(a0 + k1, lds + nb + wb);
                GLOAD_LDS16(a1 + k1, lds + nb + 4096 + wb);
                GLOAD_LDS16(b0 + k1, lds + 16384 + nb + wb);
                GLOAD_LDS16(b1 + k1, lds + 16384 + nb + 4096 + wb);
            }
            f16x8 af[4], bf[4];
#pragma unroll
            for (int i = 0; i < 4; ++i)
                af[i] = *(const f16x8*)&As[cur][64 * wr + 16 * i + l16][quad * 8];
#pragma unroll
            for (int j = 0; j < 4; ++j)
                bf[j] = *(const f16x8*)&Bs[cur][64 * wc + 16 * j + l16][quad * 8];
#pragma unroll
            for (int i = 0; i < 4; ++i)
#pragma unroll
                for (int j = 0; j < 4; ++j)
                    acc[i][j] = __builtin_amdgcn_mfma_f32_16x16x32_f16(af[i], bf[j], acc[i][j], 0, 0, 0);
            __syncthreads();   // drains next-tile DMAs (overlapped w/ MFMA) + guards buf reuse
            cur ^= 1;
        }

        float cs[4] = {}, cq[4] = {};
#pragma unroll
        for (int i = 0; i < 4; ++i) {
            int gr0 = bm + 64 * wr + 16 * i + quad * 4;
#pragma unroll
            for (int j = 0; j < 4; ++j) {
                int gc = bn0 + 64 * wc + 16 * j + l16;
                float bv = bias ? bias[gc] : 0.0f;
#pragma unroll
                for (int r = 0; r < 4; ++r) {
                    int row = gr0 + r;
                    if (row >= M) continue;
                    float v = acc[i][j][r] + bv;
                    if (res) v = s * v + om * (float)res[(long)row * ldc + gc];
                    if (Cf) Cf[(long)row * ldc + gc] = v;
                    if (Ch) Ch[(long)row * ldc + gc] = (_Float16)v;
                    if (bn_accum) { cs[j] += v; cq[j] += v * v; }
                }
            }
        }
        if (bn_accum) {
            // LDS reduce: 8 slots (wr*4+quad) per local column, overlay on As/Bs
            float* redS = (float*)&As[0][0][0];  // 4KB
            float* redQ = (float*)&Bs[0][0][0];
            int slot = wr * 4 + quad;
            __syncthreads();  // all MFMA-phase LDS reads done before overlay write
#pragma unroll
            for (int j = 0; j < 4; ++j) {
                int cl = 64 * wc + 16 * j + l16;
                redS[cl * 8 + slot] = cs[j];
                redQ[cl * 8 + slot] = cq[j];
            }
            __syncthreads();
            if (tid < 128) {
                float ssum = 0.f, qsum = 0.f;
#pragma unroll
                for (int t = 0; t < 8; ++t) {
                    ssum += redS[tid * 8 + t];
                    qsum += redQ[tid * 8 + t];
                }
                atomicAdd(&bn_accum[bn0 + tid], ssum);
                atomicAdd(&bn_accum[256 + bn0 + tid], qsum);
            }
        }
    }
}

// ---------------- attention (verified round-6): one wave per node; 32-lane halves
// split the edge list, merge online-softmax states via shfl_xor(32);
// f16 K/V strided gathers, fdot2, deferred-max rescale, fused GELU ----------------
template <int H>
__global__ __launch_bounds__(256) void attn_f16kv_kernel(
    const _Float16* __restrict__ qbase, int ldq,
    const _Float16* __restrict__ kp, const _Float16* __restrict__ vp, int ldkv,
    const float* __restrict__ p_rel,
    const int* __restrict__ row_start, const int* __restrict__ csr_src,
    _Float16* __restrict__ agg, int n)
{
    constexpr int D = 256 / H;
    constexpr int GL = D / 8;  // lanes per head group (8 ch per lane)
    int node = blockIdx.x * 4 + (threadIdx.x >> 6);  // one wave per node
    int lane = threadIdx.x & 63;
    int half = lane >> 5;     // edge-list half
    int l32 = lane & 31;      // channel lane within half
    if (node >= n) return;
    const int head = l32 / GL;
    const float scale = p_rel[head] * rsqrtf((float)D);
    const int ch = l32 * 8;  // == head*D + (l32%GL)*8 for both H=1,4
    f16x8 qv = *(const f16x8*)(qbase + (long)node * ldq + ch);
    f16x2 qp[4];
#pragma unroll
    for (int j = 0; j < 4; ++j) { qp[j][0] = qv[2 * j]; qp[j][1] = qv[2 * j + 1]; }

    const _Float16* kpc = kp + ch;
    const _Float16* vpc = vp + ch;
    int e0all = row_start[node], e1all = row_start[node + 1];
    int c0 = (e1all - e0all + 1) >> 1;      // first-half count (ceil)
    int e0 = half ? (e0all + c0) : e0all;
    int e1 = half ? e1all : (e0all + c0);

    float m = -1e30f, lsum = 0.0f;
    float a[8] = {};

    int e = e0;
    for (; e + 1 < e1; e += 2) {
        int s0 = csr_src[e], s1 = csr_src[e + 1];
        f16x8 k0 = *(const f16x8*)(kpc + (long)s0 * ldkv);
        f16x8 k1 = *(const f16x8*)(kpc + (long)s1 * ldkv);
        f16x8 v0 = *(const f16x8*)(vpc + (long)s0 * ldkv);
        f16x8 v1 = *(const f16x8*)(vpc + (long)s1 * ldkv);
        float d0 = 0.0f, d1 = 0.0f;
#pragma unroll
        for (int j = 0; j < 4; ++j) {
            f16x2 k0p = {k0[2 * j], k0[2 * j + 1]};
            f16x2 k1p = {k1[2 * j], k1[2 * j + 1]};
            d0 = __builtin_amdgcn_fdot2(qp[j], k0p, d0, false);
            d1 = __builtin_amdgcn_fdot2(qp[j], k1p, d1, false);
        }
#pragma unroll
        for (int off = 1; off < GL; off <<= 1) {
            d0 += __shfl_xor(d0, off);
            d1 += __shfl_xor(d1, off);
        }
        float al0 = d0 * scale, al1 = d1 * scale;
        float mx = fmaxf(al0, al1);
        float diff = mx - m;
        if (__builtin_expect(diff > 8.0f, 0)) {  // deferred-max rescale (rare)
            float corr = __expf(-diff);
            lsum *= corr;
#pragma unroll
            for (int j = 0; j < 8; ++j) a[j] *= corr;
            m = mx;
        }
        float w0 = __expf(al0 - m), w1 = __expf(al1 - m);
        lsum += w0 + w1;
#pragma unroll
        for (int j = 0; j < 8; ++j)
            a[j] += w0 * (float)v0[j] + w1 * (float)v1[j];
    }
    if (e < e1) {
        int s0 = csr_src[e];
        f16x8 k0 = *(const f16x8*)(kpc + (long)s0 * ldkv);
        f16x8 v0 = *(const f16x8*)(vpc + (long)s0 * ldkv);
        float d0 = 0.0f;
#pragma unroll
        for (int j = 0; j < 4; ++j) {
            f16x2 k0p = {k0[2 * j], k0[2 * j + 1]};
            d0 = __builtin_amdgcn_fdot2(qp[j], k0p, d0, false);
        }
#pragma unroll
        for (int off = 1; off < GL; off <<= 1) d0 += __shfl_xor(d0, off);
        float al0 = d0 * scale;
        float diff = al0 - m;
        if (__builtin_expect(diff > 8.0f, 0)) {
            float corr = __expf(-diff);
            lsum *= corr;
#pragma unroll
            for (int j = 0; j < 8; ++j) a[j] *= corr;
            m = al0;
        }
        float w0 = __expf(al0 - m);
        lsum += w0;
#pragma unroll
        for (int j = 0; j < 8; ++j) a[j] += w0 * (float)v0[j];
    }

    // merge the two halves' online-softmax states (cross-32 shuffles)
    float m_o = __shfl_xor(m, 32);
    float ls_o = __shfl_xor(lsum, 32);
    float mm = fmaxf(m, m_o);
    float wsf = __expf(m - mm), wo = __expf(m_o - mm);
    lsum = lsum * wsf + ls_o * wo;
#pragma unroll
    for (int j = 0; j < 8; ++j) {
        float a_o = __shfl_xor(a[j], 32);
        a[j] = a[j] * wsf + a_o * wo;
    }

    if (half == 0) {
        float inv = 1.0f / (lsum + 1e-16f);
        f16x8 o;
#pragma unroll
        for (int j = 0; j < 8; ++j) {
            float v = a[j] * inv;
            v = 0.5f * v * (1.0f + erff(v * 0.70710678118654752f));
            o[j] = (_Float16)v;
        }
        *(f16x8*)(agg + (long)node * 256 + ch) = o;
    }
}

// ---------------- BatchNorm apply (f16 in -> f16 out, stats fused in out1) ----
__global__ void bn_apply_kernel(const _Float16* __restrict__ hin, _Float16* __restrict__ hbn,
                                const float* __restrict__ stats,
                                const float* __restrict__ gamma, const float* __restrict__ beta) {
    long idx = blockIdx.x * (long)blockDim.x + threadIdx.x;  // NN*32 f16x8 groups
    if (idx >= (long)NN * 32) return;
    int cg = (int)(idx & 31) * 8;
    f16x8 hv = ((const f16x8*)hin)[idx];
    const float invn = 1.0f / 30000.0f;
    f16x8 o;
#pragma unroll
    for (int r = 0; r < 8; ++r) {
        int c = cg + r;
        float mu = stats[c] * invn;
        float var = stats[256 + c] * invn - mu * mu;
        float v = ((float)hv[r] - mu) * rsqrtf(var + 1e-5f) * gamma[c] + beta[c];
        o[r] = (_Float16)fmaxf(v, 0.0f);
    }
    ((f16x8*)hbn)[idx] = o;
}

// ---------------- launch (13 dispatches) ----------------
extern "C" void kernel_launch(void* const* d_in, const int* in_sizes, int n_in,
                              void* d_out, int out_size, void* d_ws, size_t ws_size,
                              hipStream_t stream) {
    const float* x       = (const float*)d_in[0];
    const int*   ei      = (const int*)d_in[1];
    const float* w_kqv1  = (const float*)d_in[2];
    const float* b_kqv1  = (const float*)d_in[3];
    const float* k_rel1  = (const float*)d_in[4];
    const float* v_rel1  = (const float*)d_in[5];
    const float* p_rel1  = (const float*)d_in[6];
    const float* w_out1  = (const float*)d_in[7];
    const float* b_out1  = (const float*)d_in[8];
    const float* bn_gamma = (const float*)d_in[10];
    const float* bn_beta  = (const float*)d_in[11];
    const float* w_kqv2  = (const float*)d_in[12];
    const float* b_kqv2  = (const float*)d_in[13];
    const float* k_rel2  = (const float*)d_in[14];
    const float* v_rel2  = (const float*)d_in[15];
    const float* p_rel2  = (const float*)d_in[16];
    const float* w_out2  = (const float*)d_in[17];
    const float* b_out2  = (const float*)d_in[18];
    const float* skip2   = (const float*)d_in[19];
    float* out = (float*)d_out;

    char* p = (char*)d_ws;
    auto alloc = [&](size_t bytes) -> void* {
        void* r = (void*)p;
        p += (bytes + 255) & ~(size_t)255;
        return r;
    };
    _Float16* x_h   = (_Float16*)alloc((size_t)NN * 512 * 2);   // 30.72 MB
    _Float16* kqv_h = (_Float16*)alloc((size_t)NN * 768 * 2);   // 46.08 (holds kp|q|vp)
    _Float16* agg_h = (_Float16*)alloc((size_t)NN * 256 * 2);   // 15.36
    _Float16* h16   = (_Float16*)alloc((size_t)NN * 256 * 2);   // 15.36 (pre-BN out1)
    _Float16* hbn_h = (_Float16*)alloc((size_t)NN * 256 * 2);   // 15.36 (post-BN/ReLU)
    _Float16* w1h    = (_Float16*)alloc((size_t)512 * 768 * 2); // W1 f16 row-major
    _Float16* w2h    = (_Float16*)alloc((size_t)256 * 768 * 2); // W2 f16 row-major
    _Float16* rt1    = (_Float16*)alloc((size_t)768 * 768 * 2); // Rbig1^T f16
    _Float16* rt2    = (_Float16*)alloc((size_t)768 * 768 * 2); // Rbig2^T f16
    _Float16* w1T    = (_Float16*)alloc((size_t)768 * 512 * 2); // folded, [K|Q|V] rows
    _Float16* w2T    = (_Float16*)alloc((size_t)768 * 256 * 2);
    _Float16* wout1T = (_Float16*)alloc((size_t)256 * 256 * 2);
    _Float16* wout2T = (_Float16*)alloc((size_t)256 * 256 * 2);
    float* bf1       = (float*)alloc(768 * 4);
    float* bf2       = (float*)alloc(768 * 4);
    int*   deg       = (int*)alloc((size_t)NN * 4);
    int*   row_start = (int*)alloc((size_t)(NN + 1) * 4);
    int*   pos       = (int*)alloc((size_t)NN * 4);
    int*   csr_src   = (int*)alloc((size_t)NE * 4);
    float* bnstats   = (float*)alloc(512 * 4);   // [256 sums | 256 sqsums]

    const int* esrc = ei;
    const int* edst = ei + NE;

    // ---- 1: all coalesced prep in one dispatch ----
    prep_kernel<<<PREP_BLOCKS, 256, 0, stream>>>(
        x, x_h, w_kqv1, w1h, w_kqv2, w2h, k_rel1, v_rel1, k_rel2, v_rel2,
        rt1, rt2, b_kqv1, bf1, b_kqv2, bf2, w_out1, wout1T, w_out2, wout2T,
        deg, bnstats);

    const int MB = (NN + 127) / 128;
    auto gemm_blk = [](int ntx, int nty) {
        int nt = ntx * nty;
        return nt > 1024 ? 1024 : nt;
    };

    // ---- 2-3: weight folds as tiny MFMA GEMMs ----
    mfma_gemm_kernel<<<gemm_blk(4, 6), 256, 0, stream>>>(
        rt1, 768, w1h, nullptr, w1T, 512, 768, 512, 768, 4, 6,
        nullptr, nullptr, nullptr, nullptr);
    mfma_gemm_kernel<<<gemm_blk(2, 6), 256, 0, stream>>>(
        rt2, 768, w2h, nullptr, w2T, 256, 768, 256, 768, 2, 6,
        nullptr, nullptr, nullptr, nullptr);

    // ---- 4-6: CSR build ----
    deg_kernel<<<(NE + 255) / 256, 256, 0, stream>>>(edst, deg, NE);
    scan_kernel<<<1, 1024, 0, stream>>>(deg, row_start, pos, NN);
    fill_kernel<<<(NE + 255) / 256, 256, 0, stream>>>(esrc, edst, pos, csr_src, NE);

    // ---- 7-9: layer 1 ----
    mfma_gemm_kernel<<<gemm_blk(6, MB), 256, 0, stream>>>(
        x_h, 512, w1T, nullptr, kqv_h, 768, NN, 768, 512, 6, MB,
        bf1, nullptr, nullptr, nullptr);
    attn_f16kv_kernel<4><<<(NN + 3) / 4, 256, 0, stream>>>(
        kqv_h + 256, 768, kqv_h, kqv_h + 512, 768, p_rel1, row_start, csr_src, agg_h, NN);
    mfma_gemm_kernel<<<gemm_blk(2, MB), 256, 0, stream>>>(
        agg_h, 256, wout1T, nullptr, h16, 256, NN, 256, 256, 2, MB,
        b_out1, nullptr, nullptr, bnstats);

    // ---- 10: BatchNorm apply + ReLU (f16 -> f16) ----
    bn_apply_kernel<<<(NN * 32 + 255) / 256, 256, 0, stream>>>(h16, hbn_h, bnstats, bn_gamma, bn_beta);

    // ---- 11-13: layer 2 ----
    mfma_gemm_kernel<<<gemm_blk(6, MB), 256, 0, stream>>>(
        hbn_h, 256, w2T, nullptr, kqv_h, 768, NN, 768, 256, 6, MB,
        bf2, nullptr, nullptr, nullptr);
    attn_f16kv_kernel<1><<<(NN + 3) / 4, 256, 0, stream>>>(
        kqv_h + 256, 768, kqv_h, kqv_h + 512, 768, p_rel2, row_start, csr_src, agg_h, NN);
    mfma_gemm_kernel<<<gemm_blk(2, MB), 256, 0, stream>>>(
        agg_h, 256, wout2T, out, nullptr, 256, NN, 256, 256, 2, MB,
        b_out2, hbn_h, skip2, nullptr);
}

// Round 14
// 575.748 us; speedup vs baseline: 1.0658x; 1.0658x over previous
//
#include <hip/hip_runtime.h>
#include <math.h>

#define NN 30000
#define NE 480000

typedef _Float16 f16x8 __attribute__((ext_vector_type(8)));
typedef _Float16 f16x4 __attribute__((ext_vector_type(4)));
typedef _Float16 f16x2 __attribute__((ext_vector_type(2)));
typedef float f32x4 __attribute__((ext_vector_type(4)));

// async global->LDS, 16B per lane, wave-uniform LDS base + lane*16
#define GLOAD_LDS16(gp, lp)                                        \
    __builtin_amdgcn_global_load_lds(                              \
        (const __attribute__((address_space(1))) void*)(gp),       \
        (__attribute__((address_space(3))) void*)(lp), 16, 0, 0)

// ---------------- mega prep kernel (validated round 10: coalesced only) ----
#define PREP_BLOCKS 9962
__global__ __launch_bounds__(256) void prep_kernel(
    const float* __restrict__ x, _Float16* __restrict__ x_h,
    const float* __restrict__ w_kqv1, _Float16* __restrict__ w1h,
    const float* __restrict__ w_kqv2, _Float16* __restrict__ w2h,
    const float* __restrict__ krel, const float* __restrict__ vrel,
    const float* __restrict__ krel2, const float* __restrict__ vrel2,
    _Float16* __restrict__ rt1, _Float16* __restrict__ rt2,
    const float* __restrict__ b_kqv1, float* __restrict__ bf1,
    const float* __restrict__ b_kqv2, float* __restrict__ bf2,
    const float* __restrict__ w_out1, _Float16* __restrict__ wout1T,
    const float* __restrict__ w_out2, _Float16* __restrict__ wout2T,
    int* __restrict__ deg, float* __restrict__ bnstats)
{
    const int bid = blockIdx.x, tid = threadIdx.x;
    if (bid < 7500) {                       // A: cvt x (8 elems/thread)
        long i = (long)bid * 256 + tid;     // < 1,920,000
        float4 a = ((const float4*)x)[2 * i];
        float4 b = ((const float4*)x)[2 * i + 1];
        f16x8 o = {(_Float16)a.x, (_Float16)a.y, (_Float16)a.z, (_Float16)a.w,
                   (_Float16)b.x, (_Float16)b.y, (_Float16)b.z, (_Float16)b.w};
        ((f16x8*)x_h)[i] = o;
    } else if (bid < 7692) {                // B: cvt W1 (393216 floats)
        long i = (long)(bid - 7500) * 256 + tid;
        float4 a = ((const float4*)w_kqv1)[2 * i];
        float4 b = ((const float4*)w_kqv1)[2 * i + 1];
        f16x8 o = {(_Float16)a.x, (_Float16)a.y, (_Float16)a.z, (_Float16)a.w,
                   (_Float16)b.x, (_Float16)b.y, (_Float16)b.z, (_Float16)b.w};
        ((f16x8*)w1h)[i] = o;
    } else if (bid < 7788) {                // C: cvt W2 (196608 floats)
        long i = (long)(bid - 7692) * 256 + tid;
        float4 a = ((const float4*)w_kqv2)[2 * i];
        float4 b = ((const float4*)w_kqv2)[2 * i + 1];
        f16x8 o = {(_Float16)a.x, (_Float16)a.y, (_Float16)a.z, (_Float16)a.w,
                   (_Float16)b.x, (_Float16)b.y, (_Float16)b.z, (_Float16)b.w};
        ((f16x8*)w2h)[i] = o;
    } else if (bid < 8556) {                // D: build RT1, row m = bid-7788
        int m = bid - 7788;
#pragma unroll
        for (int rep = 0; rep < 3; ++rep) {
            int d = tid + rep * 256;
            _Float16 val = (_Float16)0.0f;
            if (m < 256) {
                if (d < 256 && (d >> 6) == (m >> 6))
                    val = (_Float16)krel[(m >> 6) * 4096 + (d & 63) * 64 + (m & 63)];
            } else if (m < 512) {
                if (d == m) val = (_Float16)1.0f;
            } else {
                if (d >= 512 && ((d - 512) >> 6) == ((m - 512) >> 6))
                    val = (_Float16)vrel[((m - 512) >> 6) * 4096 +
                                         ((d - 512) & 63) * 64 + ((m - 512) & 63)];
            }
            rt1[(long)m * 768 + d] = val;
        }
    } else if (bid < 9324) {                // E: build RT2, row m = bid-8556
        int m = bid - 8556;
#pragma unroll
        for (int rep = 0; rep < 3; ++rep) {
            int d = tid + rep * 256;
            _Float16 val = (_Float16)0.0f;
            if (m < 256) {
                if (d < 256) val = (_Float16)krel2[(long)d * 256 + m];
            } else if (m < 512) {
                if (d == m) val = (_Float16)1.0f;
            } else {
                if (d >= 512) val = (_Float16)vrel2[(long)(d - 512) * 256 + (m - 512)];
            }
            rt2[(long)m * 768 + d] = val;
        }
    } else if (bid < 9327) {                // F: foldb1 ([K|Q|V])
        int n = (bid - 9324) * 256 + tid;
        float acc;
        if (n < 256) {
            int h = n >> 6, e = n & 63;
            acc = 0.f;
            for (int d = 0; d < 64; ++d) acc += b_kqv1[h * 64 + d] * krel[h * 4096 + d * 64 + e];
        } else if (n < 512) {
            acc = b_kqv1[n];
        } else {
            int m2 = n - 512, h = m2 >> 6, e = m2 & 63;
            acc = 0.f;
            for (int d = 0; d < 64; ++d) acc += b_kqv1[512 + h * 64 + d] * vrel[h * 4096 + d * 64 + e];
        }
        bf1[n] = acc;
    } else if (bid < 9330) {                // G: foldb2
        int n = (bid - 9327) * 256 + tid;
        float acc;
        if (n < 256) {
            acc = 0.f;
            for (int d = 0; d < 256; ++d) acc += b_kqv2[d] * krel2[(long)d * 256 + n];
        } else if (n < 512) {
            acc = b_kqv2[n];
        } else {
            acc = 0.f;
            for (int d = 0; d < 256; ++d) acc += b_kqv2[512 + d] * vrel2[(long)d * 256 + (n - 512)];
        }
        bf2[n] = acc;
    } else if (bid < 9586) {                // H: tcvt w_out1
        int k = bid - 9330;
        int n = tid;
        wout1T[(long)n * 256 + k] = (_Float16)w_out1[(long)k * 256 + n];
    } else if (bid < 9842) {                // I: tcvt w_out2
        int k = bid - 9586;
        int n = tid;
        wout2T[(long)n * 256 + k] = (_Float16)w_out2[(long)k * 256 + n];
    } else if (bid < 9960) {                // J: zero deg
        int i = (bid - 9842) * 256 + tid;
        if (i < NN) deg[i] = 0;
    } else {                                // K: zero bnstats
        int i = (bid - 9960) * 256 + tid;
        if (i < 512) bnstats[i] = 0.0f;
    }
}

// ---------------- CSR build ----------------
__global__ void deg_kernel(const int* __restrict__ dst, int* __restrict__ deg, int e) {
    int i = blockIdx.x * blockDim.x + threadIdx.x;
    if (i < e) atomicAdd(&deg[dst[i]], 1);
}

__global__ __launch_bounds__(1024) void scan_kernel(
    const int* __restrict__ deg, int* __restrict__ row_start,
    int* __restrict__ pos, int n)
{
    __shared__ int smem[1024];
    const int t = threadIdx.x;
    const int base = t * 32;  // 1024*32 = 32768 >= 30000
    int loc[32];
    int s = 0;
#pragma unroll
    for (int g = 0; g < 8; ++g) {
        int idx = base + g * 4;
        int4 d4;
        if (idx + 3 < n) {
            d4 = *(const int4*)(deg + idx);
        } else {
            d4.x = (idx + 0 < n) ? deg[idx + 0] : 0;
            d4.y = (idx + 1 < n) ? deg[idx + 1] : 0;
            d4.z = (idx + 2 < n) ? deg[idx + 2] : 0;
            d4.w = (idx + 3 < n) ? deg[idx + 3] : 0;
        }
        loc[g * 4 + 0] = s; s += d4.x;
        loc[g * 4 + 1] = s; s += d4.y;
        loc[g * 4 + 2] = s; s += d4.z;
        loc[g * 4 + 3] = s; s += d4.w;
    }
    smem[t] = s;
    __syncthreads();
    for (int off = 1; off < 1024; off <<= 1) {
        int tv = 0;
        if (t >= off) tv = smem[t - off];
        __syncthreads();
        smem[t] += tv;
        __syncthreads();
    }
    const int excl = smem[t] - s;
#pragma unroll
    for (int g = 0; g < 32; ++g) {
        int idx = base + g;
        if (idx < n) {
            int r = excl + loc[g];
            row_start[idx] = r;
            pos[idx] = r;
        }
    }
    if (t == 1023) row_start[n] = smem[1023];
}

__global__ void fill_kernel(const int* __restrict__ src, const int* __restrict__ dst,
                            int* __restrict__ pos, int* __restrict__ csr_src, int e) {
    int i = blockIdx.x * blockDim.x + threadIdx.x;
    if (i < e) {
        int p = atomicAdd(&pos[dst[i]], 1);
        csr_src[p] = src[i];
    }
}

// ---------------- fp16 MFMA GEMM, templated on BN (column-tile width).
// BN=128: exact r11 verified config (4 waves = 2x2, acc[4][4]).
// BN=64:  4 waves = 4 row-groups x 32 rows, acc[2][4] — doubles grid for
//         narrow-N GEMMs (N=256: 470 -> 940 blocks, fixes grid starvation).
// Double-buffered global_load_lds prefetch, one barrier per K-step. ----------
template <int BN>
__global__ __launch_bounds__(256) void mfma_gemm_kernel(
    const _Float16* __restrict__ A, int lda,
    const _Float16* __restrict__ BT,
    float* __restrict__ Cf,
    _Float16* __restrict__ Ch,
    int ldc, int M, int N, int K,
    const float* __restrict__ bias,
    const _Float16* __restrict__ res,   // f16 residual (skip blend), ld = ldc
    const float* __restrict__ skip,
    float* __restrict__ bn_accum)       // [512]: col sums then col sqsums
{
    constexpr int COLW  = BN / 64;      // waves along N (2 or 1)
    constexpr int ROWW  = 4 / COLW;     // waves along M (2 or 4)
    constexpr int WROWS = 128 / ROWW;   // rows per wave (64 or 32)
    constexpr int MI    = WROWS / 16;   // row frags per wave (4 or 2)
    constexpr int BCH   = BN / 64;      // B chunks per thread (2 or 1)
    constexpr int ABYTES = 8192;        // per-buffer A bytes (128*32*2)
    constexpr int BBYTES = BN * 64;     // per-buffer B bytes

    __shared__ __align__(16) _Float16 As[2][128][32];
    __shared__ __align__(16) _Float16 Bs[2][BN][32];
    const int tid = threadIdx.x;
    const int bm = blockIdx.y * 128, bn0 = blockIdx.x * BN;
    const int wave = tid >> 6, lane = tid & 63;
    const int wr = wave / COLW, wc = wave % COLW;
    const int l16 = lane & 15, quad = lane >> 4;
    const int r0 = tid >> 2, kc0 = (tid & 3) * 8;
    const int r1 = r0 + 64;

    int gra0 = bm + r0; if (gra0 >= M) gra0 = M - 1;  // DMA has no predication;
    int gra1 = bm + r1; if (gra1 >= M) gra1 = M - 1;  // C-store is row-guarded
    const _Float16* a0 = A + (long)gra0 * lda + kc0;
    const _Float16* a1 = A + (long)gra1 * lda + kc0;
    const _Float16* b0 = BT + (long)(bn0 + r0) * K + kc0;            // rows 0..63
    const _Float16* b1 = BT + (long)(bn0 + (BCH == 2 ? r1 : r0)) * K + kc0;  // rows 64..127 (BN=128)

    auto ldsA = (__attribute__((address_space(3))) char*)&As[0][0][0];
    auto ldsB = (__attribute__((address_space(3))) char*)&Bs[0][0][0];
    const int wb = wave * 1024;  // wave-uniform LDS base (lane*16 added by HW)

    f32x4 acc[MI][4] = {};
    const int nt = K >> 5;

    // prologue: stage tile 0 into buf 0
    GLOAD_LDS16(a0, ldsA + wb);
    GLOAD_LDS16(a1, ldsA + 4096 + wb);
    GLOAD_LDS16(b0, ldsB + wb);
    if (BCH == 2) GLOAD_LDS16(b1, ldsB + 4096 + wb);
    __syncthreads();

    int cur = 0;
    for (int t = 0; t < nt; ++t) {
        if (t + 1 < nt) {  // issue next tile's DMAs BEFORE compute (overlap)
            const int k1 = (t + 1) << 5;
            GLOAD_LDS16(a0 + k1, ldsA + (cur ^ 1) * ABYTES + wb);
            GLOAD_LDS16(a1 + k1, ldsA + (cur ^ 1) * ABYTES + 4096 + wb);
            GLOAD_LDS16(b0 + k1, ldsB + (cur ^ 1) * BBYTES + wb);
            if (BCH == 2) GLOAD_LDS16(b1 + k1, ldsB + (cur ^ 1) * BBYTES + 4096 + wb);
        }
        f16x8 af[MI], bf[4];
#pragma unroll
        for (int i = 0; i < MI; ++i)
            af[i] = *(const f16x8*)&As[cur][WROWS * wr + 16 * i + l16][quad * 8];
#pragma unroll
        for (int j = 0; j < 4; ++j)
            bf[j] = *(const f16x8*)&Bs[cur][64 * wc + 16 * j + l16][quad * 8];
#pragma unroll
        for (int i = 0; i < MI; ++i)
#pragma unroll
            for (int j = 0; j < 4; ++j)
                acc[i][j] = __builtin_amdgcn_mfma_f32_16x16x32_f16(af[i], bf[j], acc[i][j], 0, 0, 0);
        __syncthreads();   // drains next-tile DMAs (overlapped w/ MFMA) + guards buf reuse
        cur ^= 1;
    }

    float s = 1.0f, om = 0.0f;
    if (skip) {
        float sv = 1.0f / (1.0f + __expf(-skip[0]));
        s = sv; om = 1.0f - sv;
    }
    float cs[4] = {}, cq[4] = {};
#pragma unroll
    for (int i = 0; i < MI; ++i) {
        int gr0 = bm + WROWS * wr + 16 * i + quad * 4;
#pragma unroll
        for (int j = 0; j < 4; ++j) {
            int gc = bn0 + 64 * wc + 16 * j + l16;
            float bv = bias ? bias[gc] : 0.0f;
#pragma unroll
            for (int r = 0; r < 4; ++r) {
                int row = gr0 + r;
                if (row >= M) continue;
                float v = acc[i][j][r] + bv;
                if (res) v = s * v + om * (float)res[(long)row * ldc + gc];
                if (Cf) Cf[(long)row * ldc + gc] = v;
                if (Ch) Ch[(long)row * ldc + gc] = (_Float16)v;
                if (bn_accum) { cs[j] += v; cq[j] += v * v; }
            }
        }
    }
    if (bn_accum) {
        // LDS reduce: ROWW*4 slots per local column, overlay on As/Bs
        constexpr int NSLOT = ROWW * 4;      // 8 or 16; BN*NSLOT*4 = 4KB both
        float* redS = (float*)&As[0][0][0];
        float* redQ = (float*)&Bs[0][0][0];
        int slot = wr * 4 + quad;
#pragma unroll
        for (int j = 0; j < 4; ++j) {
            int cl = 64 * wc + 16 * j + l16;
            redS[cl * NSLOT + slot] = cs[j];
            redQ[cl * NSLOT + slot] = cq[j];
        }
        __syncthreads();
        if (tid < BN) {
            float ssum = 0.f, qsum = 0.f;
#pragma unroll
            for (int t = 0; t < NSLOT; ++t) {
                ssum += redS[tid * NSLOT + t];
                qsum += redQ[tid * NSLOT + t];
            }
            atomicAdd(&bn_accum[bn0 + tid], ssum);
            atomicAdd(&bn_accum[256 + bn0 + tid], qsum);
        }
    }
}

// ---------------- attention (verified round-6): one wave per node; 32-lane halves
// split the edge list, merge online-softmax states via shfl_xor(32);
// f16 K/V strided gathers, fdot2, deferred-max rescale, fused GELU ----------------
template <int H>
__global__ __launch_bounds__(256) void attn_f16kv_kernel(
    const _Float16* __restrict__ qbase, int ldq,
    const _Float16* __restrict__ kp, const _Float16* __restrict__ vp, int ldkv,
    const float* __restrict__ p_rel,
    const int* __restrict__ row_start, const int* __restrict__ csr_src,
    _Float16* __restrict__ agg, int n)
{
    constexpr int D = 256 / H;
    constexpr int GL = D / 8;  // lanes per head group (8 ch per lane)
    int node = blockIdx.x * 4 + (threadIdx.x >> 6);  // one wave per node
    int lane = threadIdx.x & 63;
    int half = lane >> 5;     // edge-list half
    int l32 = lane & 31;      // channel lane within half
    if (node >= n) return;
    const int head = l32 / GL;
    const float scale = p_rel[head] * rsqrtf((float)D);
    const int ch = l32 * 8;  // == head*D + (l32%GL)*8 for both H=1,4
    f16x8 qv = *(const f16x8*)(qbase + (long)node * ldq + ch);
    f16x2 qp[4];
#pragma unroll
    for (int j = 0; j < 4; ++j) { qp[j][0] = qv[2 * j]; qp[j][1] = qv[2 * j + 1]; }

    const _Float16* kpc = kp + ch;
    const _Float16* vpc = vp + ch;
    int e0all = row_start[node], e1all = row_start[node + 1];
    int c0 = (e1all - e0all + 1) >> 1;      // first-half count (ceil)
    int e0 = half ? (e0all + c0) : e0all;
    int e1 = half ? e1all : (e0all + c0);

    float m = -1e30f, lsum = 0.0f;
    float a[8] = {};

    int e = e0;
    for (; e + 1 < e1; e += 2) {
        int s0 = csr_src[e], s1 = csr_src[e + 1];
        f16x8 k0 = *(const f16x8*)(kpc + (long)s0 * ldkv);
        f16x8 k1 = *(const f16x8*)(kpc + (long)s1 * ldkv);
        f16x8 v0 = *(const f16x8*)(vpc + (long)s0 * ldkv);
        f16x8 v1 = *(const f16x8*)(vpc + (long)s1 * ldkv);
        float d0 = 0.0f, d1 = 0.0f;
#pragma unroll
        for (int j = 0; j < 4; ++j) {
            f16x2 k0p = {k0[2 * j], k0[2 * j + 1]};
            f16x2 k1p = {k1[2 * j], k1[2 * j + 1]};
            d0 = __builtin_amdgcn_fdot2(qp[j], k0p, d0, false);
            d1 = __builtin_amdgcn_fdot2(qp[j], k1p, d1, false);
        }
#pragma unroll
        for (int off = 1; off < GL; off <<= 1) {
            d0 += __shfl_xor(d0, off);
            d1 += __shfl_xor(d1, off);
        }
        float al0 = d0 * scale, al1 = d1 * scale;
        float mx = fmaxf(al0, al1);
        float diff = mx - m;
        if (__builtin_expect(diff > 8.0f, 0)) {  // deferred-max rescale (rare)
            float corr = __expf(-diff);
            lsum *= corr;
#pragma unroll
            for (int j = 0; j < 8; ++j) a[j] *= corr;
            m = mx;
        }
        float w0 = __expf(al0 - m), w1 = __expf(al1 - m);
        lsum += w0 + w1;
#pragma unroll
        for (int j = 0; j < 8; ++j)
            a[j] += w0 * (float)v0[j] + w1 * (float)v1[j];
    }
    if (e < e1) {
        int s0 = csr_src[e];
        f16x8 k0 = *(const f16x8*)(kpc + (long)s0 * ldkv);
        f16x8 v0 = *(const f16x8*)(vpc + (long)s0 * ldkv);
        float d0 = 0.0f;
#pragma unroll
        for (int j = 0; j < 4; ++j) {
            f16x2 k0p = {k0[2 * j], k0[2 * j + 1]};
            d0 = __builtin_amdgcn_fdot2(qp[j], k0p, d0, false);
        }
#pragma unroll
        for (int off = 1; off < GL; off <<= 1) d0 += __shfl_xor(d0, off);
        float al0 = d0 * scale;
        float diff = al0 - m;
        if (__builtin_expect(diff > 8.0f, 0)) {
            float corr = __expf(-diff);
            lsum *= corr;
#pragma unroll
            for (int j = 0; j < 8; ++j) a[j] *= corr;
            m = al0;
        }
        float w0 = __expf(al0 - m);
        lsum += w0;
#pragma unroll
        for (int j = 0; j < 8; ++j) a[j] += w0 * (float)v0[j];
    }

    // merge the two halves' online-softmax states (cross-32 shuffles)
    float m_o = __shfl_xor(m, 32);
    float ls_o = __shfl_xor(lsum, 32);
    float mm = fmaxf(m, m_o);
    float wsf = __expf(m - mm), wo = __expf(m_o - mm);
    lsum = lsum * wsf + ls_o * wo;
#pragma unroll
    for (int j = 0; j < 8; ++j) {
        float a_o = __shfl_xor(a[j], 32);
        a[j] = a[j] * wsf + a_o * wo;
    }

    if (half == 0) {
        float inv = 1.0f / (lsum + 1e-16f);
        f16x8 o;
#pragma unroll
        for (int j = 0; j < 8; ++j) {
            float v = a[j] * inv;
            v = 0.5f * v * (1.0f + erff(v * 0.70710678118654752f));
            o[j] = (_Float16)v;
        }
        *(f16x8*)(agg + (long)node * 256 + ch) = o;
    }
}

// ---------------- BatchNorm apply (f16 in -> f16 out, stats fused in out1) ----
__global__ void bn_apply_kernel(const _Float16* __restrict__ hin, _Float16* __restrict__ hbn,
                                const float* __restrict__ stats,
                                const float* __restrict__ gamma, const float* __restrict__ beta) {
    long idx = blockIdx.x * (long)blockDim.x + threadIdx.x;  // NN*32 f16x8 groups
    if (idx >= (long)NN * 32) return;
    int cg = (int)(idx & 31) * 8;
    f16x8 hv = ((const f16x8*)hin)[idx];
    const float invn = 1.0f / 30000.0f;
    f16x8 o;
#pragma unroll
    for (int r = 0; r < 8; ++r) {
        int c = cg + r;
        float mu = stats[c] * invn;
        float var = stats[256 + c] * invn - mu * mu;
        float v = ((float)hv[r] - mu) * rsqrtf(var + 1e-5f) * gamma[c] + beta[c];
        o[r] = (_Float16)fmaxf(v, 0.0f);
    }
    ((f16x8*)hbn)[idx] = o;
}

// ---------------- launch (13 dispatches) ----------------
extern "C" void kernel_launch(void* const* d_in, const int* in_sizes, int n_in,
                              void* d_out, int out_size, void* d_ws, size_t ws_size,
                              hipStream_t stream) {
    const float* x       = (const float*)d_in[0];
    const int*   ei      = (const int*)d_in[1];
    const float* w_kqv1  = (const float*)d_in[2];
    const float* b_kqv1  = (const float*)d_in[3];
    const float* k_rel1  = (const float*)d_in[4];
    const float* v_rel1  = (const float*)d_in[5];
    const float* p_rel1  = (const float*)d_in[6];
    const float* w_out1  = (const float*)d_in[7];
    const float* b_out1  = (const float*)d_in[8];
    const float* bn_gamma = (const float*)d_in[10];
    const float* bn_beta  = (const float*)d_in[11];
    const float* w_kqv2  = (const float*)d_in[12];
    const float* b_kqv2  = (const float*)d_in[13];
    const float* k_rel2  = (const float*)d_in[14];
    const float* v_rel2  = (const float*)d_in[15];
    const float* p_rel2  = (const float*)d_in[16];
    const float* w_out2  = (const float*)d_in[17];
    const float* b_out2  = (const float*)d_in[18];
    const float* skip2   = (const float*)d_in[19];
    float* out = (float*)d_out;

    char* p = (char*)d_ws;
    auto alloc = [&](size_t bytes) -> void* {
        void* r = (void*)p;
        p += (bytes + 255) & ~(size_t)255;
        return r;
    };
    _Float16* x_h   = (_Float16*)alloc((size_t)NN * 512 * 2);   // 30.72 MB
    _Float16* kqv_h = (_Float16*)alloc((size_t)NN * 768 * 2);   // 46.08 (holds kp|q|vp)
    _Float16* agg_h = (_Float16*)alloc((size_t)NN * 256 * 2);   // 15.36
    _Float16* h16   = (_Float16*)alloc((size_t)NN * 256 * 2);   // 15.36 (pre-BN out1)
    _Float16* hbn_h = (_Float16*)alloc((size_t)NN * 256 * 2);   // 15.36 (post-BN/ReLU)
    _Float16* w1h    = (_Float16*)alloc((size_t)512 * 768 * 2); // W1 f16 row-major
    _Float16* w2h    = (_Float16*)alloc((size_t)256 * 768 * 2); // W2 f16 row-major
    _Float16* rt1    = (_Float16*)alloc((size_t)768 * 768 * 2); // Rbig1^T f16
    _Float16* rt2    = (_Float16*)alloc((size_t)768 * 768 * 2); // Rbig2^T f16
    _Float16* w1T    = (_Float16*)alloc((size_t)768 * 512 * 2); // folded, [K|Q|V] rows
    _Float16* w2T    = (_Float16*)alloc((size_t)768 * 256 * 2);
    _Float16* wout1T = (_Float16*)alloc((size_t)256 * 256 * 2);
    _Float16* wout2T = (_Float16*)alloc((size_t)256 * 256 * 2);
    float* bf1       = (float*)alloc(768 * 4);
    float* bf2       = (float*)alloc(768 * 4);
    int*   deg       = (int*)alloc((size_t)NN * 4);
    int*   row_start = (int*)alloc((size_t)(NN + 1) * 4);
    int*   pos       = (int*)alloc((size_t)NN * 4);
    int*   csr_src   = (int*)alloc((size_t)NE * 4);
    float* bnstats   = (float*)alloc(512 * 4);   // [256 sums | 256 sqsums]

    const int* esrc = ei;
    const int* edst = ei + NE;

    // ---- 1: all coalesced prep in one dispatch ----
    prep_kernel<<<PREP_BLOCKS, 256, 0, stream>>>(
        x, x_h, w_kqv1, w1h, w_kqv2, w2h, k_rel1, v_rel1, k_rel2, v_rel2,
        rt1, rt2, b_kqv1, bf1, b_kqv2, bf2, w_out1, wout1T, w_out2, wout2T,
        deg, bnstats);

    // ---- 2-3: weight folds as tiny MFMA GEMMs ----
    mfma_gemm_kernel<128><<<dim3(4, 6), 256, 0, stream>>>(
        rt1, 768, w1h, nullptr, w1T, 512, 768, 512, 768, nullptr, nullptr, nullptr, nullptr);
    mfma_gemm_kernel<128><<<dim3(2, 6), 256, 0, stream>>>(
        rt2, 768, w2h, nullptr, w2T, 256, 768, 256, 768, nullptr, nullptr, nullptr, nullptr);

    // ---- 4-6: CSR build ----
    deg_kernel<<<(NE + 255) / 256, 256, 0, stream>>>(edst, deg, NE);
    scan_kernel<<<1, 1024, 0, stream>>>(deg, row_start, pos, NN);
    fill_kernel<<<(NE + 255) / 256, 256, 0, stream>>>(esrc, edst, pos, csr_src, NE);

    const int MB = (NN + 127) / 128;

    // ---- 7-9: layer 1 ----
    mfma_gemm_kernel<128><<<dim3(6, MB), 256, 0, stream>>>(
        x_h, 512, w1T, nullptr, kqv_h, 768, NN, 768, 512, bf1, nullptr, nullptr, nullptr);
    attn_f16kv_kernel<4><<<(NN + 3) / 4, 256, 0, stream>>>(
        kqv_h + 256, 768, kqv_h, kqv_h + 512, 768, p_rel1, row_start, csr_src, agg_h, NN);
    // out1: BN=64 -> 4x235 = 940 blocks (was 470, grid-starved)
    mfma_gemm_kernel<64><<<dim3(4, MB), 256, 0, stream>>>(
        agg_h, 256, wout1T, nullptr, h16, 256, NN, 256, 256, b_out1, nullptr, nullptr, bnstats);

    // ---- 10: BatchNorm apply + ReLU (f16 -> f16) ----
    bn_apply_kernel<<<(NN * 32 + 255) / 256, 256, 0, stream>>>(h16, hbn_h, bnstats, bn_gamma, bn_beta);

    // ---- 11-13: layer 2 ----
    mfma_gemm_kernel<128><<<dim3(6, MB), 256, 0, stream>>>(
        hbn_h, 256, w2T, nullptr, kqv_h, 768, NN, 768, 256, bf2, nullptr, nullptr, nullptr);
    attn_f16kv_kernel<1><<<(NN + 3) / 4, 256, 0, stream>>>(
        kqv_h + 256, 768, kqv_h, kqv_h + 512, 768, p_rel2, row_start, csr_src, agg_h, NN);
    // out2: BN=64 + skip residual
    mfma_gemm_kernel<64><<<dim3(4, MB), 256, 0, stream>>>(
        agg_h, 256, wout2T, out, nullptr, 256, NN, 256, 256, b_out2, hbn_h, skip2, nullptr);
}